// Round 1
// baseline (564.853 us; speedup 1.0000x reference)
//
#include <hip/hip_runtime.h>
#include <float.h>

// Problem constants (match reference): B=32, N=M=128, D=256, WEIGHT=1.0
#define Bc 32
#define Nn 128
#define Dd 256

#define BIGV 1e37f  // "used column" sentinel: c - (-BIGV + s_u) rounds to exactly BIGV
                    // for |c|,|s_u| << 1e29, so used columns never win the argmin.

// ---------------------------------------------------------------------------
// DPP helpers. dpp_ctrl must be a compile-time constant.
// ---------------------------------------------------------------------------
template <int CTRL>
__device__ __forceinline__ float dpp_addsrc(float x) {  // old = 0 for untouched lanes
    return __int_as_float(__builtin_amdgcn_update_dpp(0, __float_as_int(x), CTRL,
                                                      0xf, 0xf, false));
}
__device__ __forceinline__ float wave_sum_lane63(float x) {
    x += dpp_addsrc<0x121>(x);  // row_ror:1
    x += dpp_addsrc<0x122>(x);  // row_ror:2
    x += dpp_addsrc<0x124>(x);  // row_ror:4
    x += dpp_addsrc<0x128>(x);  // row_ror:8
    x += dpp_addsrc<0x142>(x);  // row_bcast:15
    x += dpp_addsrc<0x143>(x);  // row_bcast:31
    return x;                   // lane 63 = total
}

template <int CTRL>
__device__ __forceinline__ unsigned dpp_movu(unsigned x) {  // old = UINT_MAX
    return (unsigned)__builtin_amdgcn_update_dpp((int)0xFFFFFFFFu, (int)x, CTRL,
                                                 0xf, 0xf, false);
}
__device__ __forceinline__ unsigned wave_umin_lane63(unsigned x) {
    x = min(x, dpp_movu<0x121>(x));
    x = min(x, dpp_movu<0x122>(x));
    x = min(x, dpp_movu<0x124>(x));
    x = min(x, dpp_movu<0x128>(x));
    x = min(x, dpp_movu<0x142>(x));
    x = min(x, dpp_movu<0x143>(x));
    return x;                   // lane 63 = min of all 64 lanes
}

template <int CTRL>
__device__ __forceinline__ float dpp_movf(float x) {  // old = FLT_MAX
    return __int_as_float(__builtin_amdgcn_update_dpp(0x7f7fffff, __float_as_int(x),
                                                      CTRL, 0xf, 0xf, false));
}
// two-min (min, second-min counting multiplicity) combine step
template <int CTRL>
__device__ __forceinline__ void dpp2min_step(float& m1, float& m2) {
    float o1 = dpp_movf<CTRL>(m1);
    float o2 = dpp_movf<CTRL>(m2);
    float n1 = fminf(m1, o1);
    m2 = fminf(fmaxf(m1, o1), fminf(m2, o2));
    m1 = n1;
}

__device__ __forceinline__ float readlane_f(float v, int lane) {
    return __int_as_float(__builtin_amdgcn_readlane(__float_as_int(v), lane));
}

// ---------------------------------------------------------------------------
// Kernel 1: pairwise MSE cost, written INTERLEAVED:
//   storage row i holds float2 pairs {cost(i,k), cost(i,k+64)} for k=0..63,
//   i.e. column j lands at float offset (j<64 ? 2j : 2(j-64)+1).
// This lets the hungarian kernel fetch both of a lane's owned columns with a
// single ds_read_b64 (halves LDS issue count on the serial critical path).
// ---------------------------------------------------------------------------
__global__ __launch_bounds__(64) void cost_kernel(const float* __restrict__ P,
                                                  const float* __restrict__ G,
                                                  float* __restrict__ C,
                                                  float* __restrict__ out) {
    const int b = blockIdx.y;
    const int i = blockIdx.x;
    const int t = threadIdx.x;

    if (b == 0 && i == 0 && t == 0) *out = 0.0f;

    const float4 pv = ((const float4*)(P + ((size_t)b * Nn + i) * Dd))[t];
    const float4* g4 = (const float4*)(G + (size_t)b * Nn * Dd);
    float* crow = C + ((size_t)b * Nn + i) * Nn;

    for (int j = 0; j < Nn; j += 2) {
        float4 gv0 = g4[(size_t)j * 64 + t];
        float4 gv1 = g4[(size_t)(j + 1) * 64 + t];
        float dx0 = pv.x - gv0.x, dy0 = pv.y - gv0.y, dz0 = pv.z - gv0.z, dw0 = pv.w - gv0.w;
        float dx1 = pv.x - gv1.x, dy1 = pv.y - gv1.y, dz1 = pv.z - gv1.z, dw1 = pv.w - gv1.w;
        float s0 = dx0 * dx0 + dy0 * dy0 + dz0 * dz0 + dw0 * dw0;
        float s1 = dx1 * dx1 + dy1 * dy1 + dz1 * dz1 + dw1 * dw1;
        s0 = wave_sum_lane63(s0);
        s1 = wave_sum_lane63(s1);
        if (t == 63) {
            // j and j+1 are in the same half (j even), so offsets are base, base+2
            int base = (j < 64) ? (2 * j) : (2 * (j - 64) + 1);
            crow[base]     = s0 * (1.0f / (float)Dd);
            crow[base + 2] = s1 * (1.0f / (float)Dd);
        }
    }
}

// ---------------------------------------------------------------------------
// Kernel 2: LAPJV-style Hungarian, one single-wave block per batch.
// Same algorithm as before; this revision is critical-path surgery on the
// Phase-3 Dijkstra inner loop (the 0.74%-VALUBusy serial-latency bottleneck):
//   - cost matrix interleaved -> one ds_read_b64 per iteration (was 2x b32)
//   - pPk = pA | pB<<8 packed per lane (p is constant within a run) ->
//     p-lookup is a single readlane + SALU byte extract, so the row prefetch
//     ds_read issues earlier in the chain
//   - bA/bB = (used ? -BIGV : v) + s_u pre-folded during the LDS shadow:
//     post-LDS relax is sub -> max -> fmin -> pack -> umin chain, with used
//     columns excluded by the BIGV sentinel instead of a per-iter cndmask
//   - branchless used/rU marking and dual updates, all in the LDS shadow
// Numerics identical to previous version (packed-key truncation <=2^-15 rel,
// clamps keep reduced costs >= 0).
// ---------------------------------------------------------------------------
__global__ __launch_bounds__(64) void hungarian_kernel(const float* __restrict__ Call,
                                                       float* __restrict__ out) {
    const int b = blockIdx.x;
    const int t = threadIdx.x;

    __shared__ float Csh[Nn * Nn];  // 64 KB, interleaved layout (see cost_kernel)
    __shared__ int claim[Nn];

    // stage this batch's cost matrix into LDS (coalesced float4; layout-agnostic)
    {
        const float4* src = (const float4*)(Call + (size_t)b * Nn * Nn);
        float4* dst = (float4*)Csh;
#pragma unroll
        for (int k = 0; k < (Nn * Nn / 4) / 64; ++k)
            dst[k * 64 + t] = src[k * 64 + t];
    }
    claim[t] = 0x7fffffff;
    claim[t + 64] = 0x7fffffff;
    __syncthreads();

    const float2* C2 = (const float2*)Csh;  // C2[i*64 + t] = {cost(i,t), cost(i,t+64)}

    // ---- Phase 1: column reduction ----
    float bestA = FLT_MAX, bestB = FLT_MAX;
    int argA = 0, argB = 0;  // 0-based argmin row per owned column
#pragma unroll 8
    for (int i = 0; i < Nn; ++i) {
        float2 c = C2[i * 64 + t];
        if (c.x < bestA) { bestA = c.x; argA = i; }
        if (c.y < bestB) { bestB = c.y; argB = i; }
    }
    float vA = bestA, vB = bestB;     // column potentials (reduced costs >= 0, u=0)
    atomicMin(&claim[argA], t);       // column (0-based) claims its argmin row
    atomicMin(&claim[argB], t + 64);
    __syncthreads();

    float uA = 0.0f, uB = 0.0f;       // row potentials (rows t+1, t+65)
    float wA = 0.0f, wB = 0.0f;       // w[j] = u[p[j]]
    int pA = 0, pB = 0;               // row assigned to column (0 = free)
    if (claim[argA] == t)      pA = argA + 1;
    if (claim[argB] == t + 64) pB = argB + 1;

    unsigned long long fmA = __ballot(claim[t] == 0x7fffffff);       // free rows 1..64
    unsigned long long fmB = __ballot(claim[t + 64] == 0x7fffffff);  // free rows 65..128

    // ---- Phase 2: augmenting row reduction (2 passes, bounded, with steal) ----
    for (int pass = 0; pass < 2; ++pass) {
        if (!(fmA | fmB)) break;
        unsigned long long remA = fmA, remB = fmB;
        int guard = 0;
        while ((remA | remB) != 0ull && guard++ < 256) {
            int l, i, slotR;
            if (remA) { l = __ffsll(remA) - 1; remA &= remA - 1; i = l + 1;  slotR = 0;
                        if (!((fmA >> l) & 1)) continue; }
            else      { l = __ffsll(remB) - 1; remB &= remB - 1; i = l + 65; slotR = 1;
                        if (!((fmB >> l) & 1)) continue; }

            float2 cc = C2[(i - 1) * 64 + t];
            float cur0 = cc.x - vA;
            float cur1 = cc.y - vB;
            float m1 = fminf(cur0, cur1);
            float m2 = fmaxf(cur0, cur1);
            dpp2min_step<0x121>(m1, m2);
            dpp2min_step<0x122>(m1, m2);
            dpp2min_step<0x124>(m1, m2);
            dpp2min_step<0x128>(m1, m2);
            dpp2min_step<0x142>(m1, m2);
            dpp2min_step<0x143>(m1, m2);
            float s_m1 = readlane_f(m1, 63);
            float s_m2 = readlane_f(m2, 63);

            unsigned long long b0 = __ballot(cur0 == s_m1);
            unsigned long long b1 = __ballot(cur1 == s_m1);
            int j1 = b0 ? __ffsll(b0) : (__ffsll(b1) + 64);  // 1-based column
            int lane1 = (j1 - 1) & 63, slot1 = (j1 - 1) >> 6;

            // u[i] = second-min  (dual-feasible regardless of what follows)
            if (t == l) { if (slotR == 0) uA = s_m2; else uB = s_m2; }

            int k0 = __builtin_amdgcn_readlane(slot1 ? pB : pA, lane1);
            bool strict = (s_m1 < s_m2);
            if (!strict && k0 != 0) continue;  // tie & occupied: leave row free

            if (t == lane1) {
                if (slot1 == 0) { vA += s_m1 - s_m2; pA = i; wA = s_m2; }
                else            { vB += s_m1 - s_m2; pB = i; wB = s_m2; }
            }
            if (slotR == 0) fmA &= ~(1ull << l); else fmB &= ~(1ull << l);
            if (k0 != 0) {  // stolen row becomes free again
                int kl = (k0 - 1) & 63;
                if (k0 <= 64) { fmA |= 1ull << kl; remA |= 1ull << kl; }
                else          { fmB |= 1ull << kl; remB |= 1ull << kl; }
            }
        }
    }

    // ---- Phase 3: Dijkstra shortest augmenting path for leftover free rows ----
    for (int slotR = 0; slotR < 2; ++slotR) {
        unsigned long long mask = slotR ? fmB : fmA;
        while (mask) {
            int l = __ffsll(mask) - 1;
            mask &= mask - 1;
            int i = l + 1 + slotR * 64;  // 1-based free row

            // p[] is constant during one Dijkstra run: pack both owned columns'
            // assignments into one VGPR for a single-hop readlane lookup.
            int pPk = (pA & 0xFF) | ((pB & 0xFF) << 8);

            float minvA = FLT_MAX, minvB = FLT_MAX;
            int wayA = 0, wayB = 0;
            bool usedA = false, usedB = false;
            bool rUA = (slotR == 0) && (t == l);
            bool rUB = (slotR == 1) && (t == l);

            int s_j0 = 0;
            float s_u = readlane_f(slotR ? uB : uA, l);  // u[i] from ARR
            int s_j1;

            float bA = vA + s_u;   // pre-folded relax subtrahend (col A)
            float bB = vB + s_u;   // (col B)

            float2 c = C2[(i - 1) * 64 + t];  // initial row load (row i)

            for (;;) {
                // relax: used columns produce exactly BIGV (bA = -BIGV + s_u
                // rounds to -BIGV), so they never beat real candidates.
                float cur0 = fmaxf(c.x - bA, 0.0f);
                float cur1 = fmaxf(c.y - bB, 0.0f);
                bool u0 = (cur0 < minvA) && !usedA;
                bool u1 = (cur1 < minvB) && !usedB;
                wayA = u0 ? s_j0 : wayA;
                wayB = u1 ? s_j0 : wayB;
                minvA = fminf(minvA, cur0);
                minvB = fminf(minvB, cur1);

                // packed-key argmin: (value_bits & ~0xFF) | col0based
                unsigned kA = (__float_as_uint(minvA) & 0xFFFFFF00u) | (unsigned)t;
                unsigned kB = (__float_as_uint(minvB) & 0xFFFFFF00u) | (unsigned)(t + 64);
                unsigned k = wave_umin_lane63(min(kA, kB));
                unsigned s_key = (unsigned)__builtin_amdgcn_readlane((int)k, 63);

                int s_col = (int)(s_key & 0xFFu);  // 0-based column
                s_j1 = s_col + 1;
                float s_delta = __uint_as_float(s_key & 0xFFFFFF00u);

                // single-hop p lookup, then issue the row prefetch ASAP
                int s_pp = __builtin_amdgcn_readlane(pPk, s_col & 63);
                int s_p = (s_pp >> ((s_col >> 6) << 3)) & 0xFF;
                int nrow = (s_p > 0 ? s_p : 1) - 1;
                float2 nc = C2[nrow * 64 + t];  // latency hides under updates below

                // w lookup (independent of prefetch; runs in LDS shadow)
                float s_wA = readlane_f(wA, s_col & 63);
                float s_wB = readlane_f(wB, s_col & 63);
                float s_w = (s_col >> 6) ? s_wB : s_wA;

                // dual updates (branchless, in LDS shadow)
                vA -= usedA ? s_delta : 0.0f;
                wA += usedA ? s_delta : 0.0f;
                vB -= usedB ? s_delta : 0.0f;
                wB += usedB ? s_delta : 0.0f;
                uA += rUA ? s_delta : 0.0f;
                uB += rUB ? s_delta : 0.0f;
                // used lanes hold ~BIGV; BIGV - delta == BIGV exactly, so no select
                minvA = fmaxf(minvA - s_delta, 0.0f);
                minvB = fmaxf(minvB - s_delta, 0.0f);

                if (s_p == 0) break;  // augmenting path found at s_j1

                // mark used column + new tree row (branchless)
                bool mk0 = (s_col == t);
                bool mk1 = (s_col == t + 64);
                usedA = usedA || mk0;
                usedB = usedB || mk1;
                minvA = mk0 ? BIGV : minvA;
                minvB = mk1 ? BIGV : minvB;
                int r = s_p - 1;
                rUA = rUA || (r == t);
                rUB = rUB || (r == t + 64);

                s_j0 = s_j1;
                s_u = s_w;
                bA = (usedA ? -BIGV : vA) + s_u;
                bB = (usedB ? -BIGV : vB) + s_u;
                c = nc;
            }

            // augment along way[] chain (uniform serial walk)
            int s_j = s_j1;
            while (s_j) {
                int lane = (s_j - 1) & 63;
                int slot = (s_j - 1) >> 6;
                int s_jprev = __builtin_amdgcn_readlane(slot ? wayB : wayA, lane);
                int s_pnew;
                if (s_jprev == 0) {
                    s_pnew = i;
                } else {
                    int lp = (s_jprev - 1) & 63;
                    int sp = (s_jprev - 1) >> 6;
                    s_pnew = __builtin_amdgcn_readlane(sp ? pB : pA, lp);
                }
                int rl = (s_pnew - 1) & 63;
                int rs = (s_pnew - 1) >> 6;
                float s_unew = readlane_f(rs ? uB : uA, rl);  // w[j] = u[p[j]]
                if (t == lane) {
                    if (slot == 0) { pA = s_pnew; wA = s_unew; }
                    else           { pB = s_pnew; wB = s_unew; }
                }
                s_j = s_jprev;
            }
        }
    }

    // ---- gather matched costs: column jA=t -> row pA-1, col jB=t+64 -> pB-1 ----
    float tot = Csh[(pA - 1) * Nn + 2 * t] + Csh[(pB - 1) * Nn + 2 * t + 1];
    tot = wave_sum_lane63(tot);

    if (t == 63) {
        // loss = sum_b (total_b / N) / B * WEIGHT
        atomicAdd(out, tot * (1.0f / ((float)Nn * (float)Bc)));
    }
}

extern "C" void kernel_launch(void* const* d_in, const int* in_sizes, int n_in,
                              void* d_out, int out_size, void* d_ws, size_t ws_size,
                              hipStream_t stream) {
    const float* P = (const float*)d_in[0];   // batch_prediction  [32,128,256] f32
    const float* G = (const float*)d_in[1];   // batch_groundtruth [32,128,256] f32
    float* out = (float*)d_out;               // [1] f32
    float* C = (float*)d_ws;                  // cost scratch: 32*128*128 f32 = 2 MB

    dim3 gcost(Nn, Bc);
    cost_kernel<<<gcost, 64, 0, stream>>>(P, G, C, out);
    hungarian_kernel<<<Bc, 64, 0, stream>>>(C, out);
}

// Round 2
// 534.592 us; speedup vs baseline: 1.0566x; 1.0566x over previous
//
#include <hip/hip_runtime.h>
#include <float.h>

// Problem constants (match reference): B=32, N=M=128, D=256, WEIGHT=1.0
#define Bc 32
#define Nn 128
#define Dd 256

// ---------------------------------------------------------------------------
// DPP helpers. dpp_ctrl must be a compile-time constant.
// Reduction to lane 63: ror 1/2/4/8 within 16-lane rows (all sources valid),
// then row_bcast:15 / row_bcast:31 fold rows; lane 63 ends with the full
// 64-lane reduction (standard CDNA pattern).
// ---------------------------------------------------------------------------
template <int CTRL>
__device__ __forceinline__ float dpp_addsrc(float x) {  // old = 0 for untouched lanes
    return __int_as_float(__builtin_amdgcn_update_dpp(0, __float_as_int(x), CTRL,
                                                      0xf, 0xf, false));
}
__device__ __forceinline__ float wave_sum_lane63(float x) {
    x += dpp_addsrc<0x121>(x);  // row_ror:1
    x += dpp_addsrc<0x122>(x);  // row_ror:2
    x += dpp_addsrc<0x124>(x);  // row_ror:4
    x += dpp_addsrc<0x128>(x);  // row_ror:8
    x += dpp_addsrc<0x142>(x);  // row_bcast:15
    x += dpp_addsrc<0x143>(x);  // row_bcast:31
    return x;                   // lane 63 = total
}

template <int CTRL>
__device__ __forceinline__ unsigned dpp_movu(unsigned x) {  // old = UINT_MAX
    return (unsigned)__builtin_amdgcn_update_dpp((int)0xFFFFFFFFu, (int)x, CTRL,
                                                 0xf, 0xf, false);
}
__device__ __forceinline__ unsigned wave_umin_lane63(unsigned x) {
    x = min(x, dpp_movu<0x121>(x));
    x = min(x, dpp_movu<0x122>(x));
    x = min(x, dpp_movu<0x124>(x));
    x = min(x, dpp_movu<0x128>(x));
    x = min(x, dpp_movu<0x142>(x));
    x = min(x, dpp_movu<0x143>(x));
    return x;                   // lane 63 = min of all 64 lanes
}

template <int CTRL>
__device__ __forceinline__ float dpp_movf(float x) {  // old = FLT_MAX
    return __int_as_float(__builtin_amdgcn_update_dpp(0x7f7fffff, __float_as_int(x),
                                                      CTRL, 0xf, 0xf, false));
}
// two-min (min, second-min counting multiplicity) combine step
template <int CTRL>
__device__ __forceinline__ void dpp2min_step(float& m1, float& m2) {
    float o1 = dpp_movf<CTRL>(m1);
    float o2 = dpp_movf<CTRL>(m2);
    float n1 = fminf(m1, o1);
    m2 = fminf(fmaxf(m1, o1), fminf(m2, o2));
    m1 = n1;
}

__device__ __forceinline__ float readlane_f(float v, int lane) {
    return __int_as_float(__builtin_amdgcn_readlane(__float_as_int(v), lane));
}

// ---------------------------------------------------------------------------
// Kernel 1: pairwise MSE cost.  cost[b,i,j] = sum_d (p[b,i,d]-g[b,j,d])^2 / D
// One wave per (b,i) row; lane t holds float4 of p[b,i]. DPP-add reduction
// (pure VALU). Block (0,0) lane 0 also zeroes the output scalar.
// ---------------------------------------------------------------------------
__global__ __launch_bounds__(64) void cost_kernel(const float* __restrict__ P,
                                                  const float* __restrict__ G,
                                                  float* __restrict__ C,
                                                  float* __restrict__ out) {
    const int b = blockIdx.y;
    const int i = blockIdx.x;
    const int t = threadIdx.x;

    if (b == 0 && i == 0 && t == 0) *out = 0.0f;

    const float4 pv = ((const float4*)(P + ((size_t)b * Nn + i) * Dd))[t];
    const float4* g4 = (const float4*)(G + (size_t)b * Nn * Dd);
    float* crow = C + ((size_t)b * Nn + i) * Nn;

    for (int j = 0; j < Nn; j += 2) {
        float4 gv0 = g4[(size_t)j * 64 + t];
        float4 gv1 = g4[(size_t)(j + 1) * 64 + t];
        float dx0 = pv.x - gv0.x, dy0 = pv.y - gv0.y, dz0 = pv.z - gv0.z, dw0 = pv.w - gv0.w;
        float dx1 = pv.x - gv1.x, dy1 = pv.y - gv1.y, dz1 = pv.z - gv1.z, dw1 = pv.w - gv1.w;
        float s0 = dx0 * dx0 + dy0 * dy0 + dz0 * dz0 + dw0 * dw0;
        float s1 = dx1 * dx1 + dy1 * dy1 + dz1 * dz1 + dw1 * dw1;
        s0 = wave_sum_lane63(s0);
        s1 = wave_sum_lane63(s1);
        if (t == 63) {
            crow[j]     = s0 * (1.0f / (float)Dd);
            crow[j + 1] = s1 * (1.0f / (float)Dd);
        }
    }
}

// ---------------------------------------------------------------------------
// Kernel 2: LAPJV-style Hungarian, one single-wave block per batch.
//   Phase 1:   column reduction + greedy zero-edge match.
//   Phase 1.5: reduction transfer (NEW): for each assigned row i->j1,
//              mu = min_{j != j1}(c_ij - v_j); u_i = mu; v_{j1} -= mu.
//              Tightens duals -> shorter ARR steal chains + Dijkstra paths.
//              Feasibility: v_j <= col-min throughout so mu >= 0; slack at
//              (i,j1) stays 0; w[j1] = u[p[j1]] updated alongside.
//   Phase 2:   augmenting row reduction (2 bounded passes with steal).
//   Phase 3:   Dijkstra shortest augmenting path for leftover free rows,
//              packed-key argmin + LDS next-row prefetch.
// All phases maintain (eps-)dual feasibility + complementary slackness;
// packed-key drops 8 mantissa bits of minv (<=2^-15 rel perturbation) and
// clamps keep reduced costs >= 0; loss error ~1e-3 << threshold.
// State: lane t owns columns jA=t+1, jB=t+65 (v, minv, way, used, p, w=u[p])
// and rows t+1, t+65 (u, rU). No LDS state / barriers in the hot loop.
// ---------------------------------------------------------------------------
__global__ __launch_bounds__(64) void hungarian_kernel(const float* __restrict__ Call,
                                                       float* __restrict__ out) {
    const int b = blockIdx.x;
    const int t = threadIdx.x;

    __shared__ float Csh[Nn * Nn];  // 64 KB
    __shared__ int claim[Nn];

    // stage this batch's cost matrix into LDS (coalesced float4)
    {
        const float4* src = (const float4*)(Call + (size_t)b * Nn * Nn);
        float4* dst = (float4*)Csh;
#pragma unroll
        for (int k = 0; k < (Nn * Nn / 4) / 64; ++k)
            dst[k * 64 + t] = src[k * 64 + t];
    }
    claim[t] = 0x7fffffff;
    claim[t + 64] = 0x7fffffff;
    __syncthreads();

    // ---- Phase 1: column reduction ----
    float bestA = FLT_MAX, bestB = FLT_MAX;
    int argA = 0, argB = 0;  // 0-based argmin row per owned column
    for (int i = 0; i < Nn; ++i) {
        float c0 = Csh[i * Nn + t];
        float c1 = Csh[i * Nn + t + 64];
        if (c0 < bestA) { bestA = c0; argA = i; }
        if (c1 < bestB) { bestB = c1; argB = i; }
    }
    float vA = bestA, vB = bestB;     // column potentials (reduced costs >= 0, u=0)
    atomicMin(&claim[argA], t);       // column (0-based) claims its argmin row
    atomicMin(&claim[argB], t + 64);
    __syncthreads();

    float uA = 0.0f, uB = 0.0f;       // row potentials (rows t+1, t+65)
    float wA = 0.0f, wB = 0.0f;       // w[j] = u[p[j]]
    int pA = 0, pB = 0;               // row assigned to column (0 = free)
    if (claim[argA] == t)      pA = argA + 1;
    if (claim[argB] == t + 64) pB = argB + 1;

    unsigned long long fmA = __ballot(claim[t] == 0x7fffffff);       // free rows 1..64
    unsigned long long fmB = __ballot(claim[t + 64] == 0x7fffffff);  // free rows 65..128

    // ---- Phase 1.5: reduction transfer (serial over assigned rows) ----
    {
        int rcA = claim[t];        // column (0-based) that won row t+1, or INT_MAX
        int rcB = claim[t + 64];   // column that won row t+65, or INT_MAX
        float c0 = Csh[t];         // prefetch row 0
        float c1 = Csh[t + 64];
        for (int r = 0; r < Nn; ++r) {
            int s_c = __builtin_amdgcn_readlane((r & 64) ? rcB : rcA, r & 63);
            int pr = (r + 1) & (Nn - 1);          // wrap-safe next-row prefetch
            float n0 = Csh[pr * Nn + t];
            float n1 = Csh[pr * Nn + t + 64];
            if (s_c != 0x7fffffff) {              // row r+1 is assigned to col s_c
                bool ex0 = (t == s_c);            // exclude the assigned column
                bool ex1 = (t + 64 == s_c);
                float cur0 = ex0 ? FLT_MAX : (c0 - vA);
                float cur1 = ex1 ? FLT_MAX : (c1 - vB);
                float m = fminf(cur0, cur1);
                m = fminf(m, dpp_movf<0x121>(m));
                m = fminf(m, dpp_movf<0x122>(m));
                m = fminf(m, dpp_movf<0x124>(m));
                m = fminf(m, dpp_movf<0x128>(m));
                m = fminf(m, dpp_movf<0x142>(m));
                m = fminf(m, dpp_movf<0x143>(m));
                float mu = readlane_f(m, 63);     // mu >= 0 (v_j <= col min)
                if (ex0) { vA -= mu; wA = mu; }   // v[j1] -= mu; w[j1] = u[row]
                if (ex1) { vB -= mu; wB = mu; }
                if (t == (r & 63)) {              // u[row r+1] = mu
                    if (r < 64) uA = mu; else uB = mu;
                }
            }
            c0 = n0; c1 = n1;
        }
    }

    // ---- Phase 2: augmenting row reduction (2 passes, bounded, with steal) ----
    for (int pass = 0; pass < 2; ++pass) {
        if (!(fmA | fmB)) break;
        unsigned long long remA = fmA, remB = fmB;
        int guard = 0;
        while ((remA | remB) != 0ull && guard++ < 256) {
            int l, i, slotR;
            if (remA) { l = __ffsll(remA) - 1; remA &= remA - 1; i = l + 1;  slotR = 0;
                        if (!((fmA >> l) & 1)) continue; }
            else      { l = __ffsll(remB) - 1; remB &= remB - 1; i = l + 65; slotR = 1;
                        if (!((fmB >> l) & 1)) continue; }

            const float* crow = &Csh[(i - 1) * Nn];
            float cur0 = crow[t] - vA;
            float cur1 = crow[t + 64] - vB;
            float m1 = fminf(cur0, cur1);
            float m2 = fmaxf(cur0, cur1);
            dpp2min_step<0x121>(m1, m2);
            dpp2min_step<0x122>(m1, m2);
            dpp2min_step<0x124>(m1, m2);
            dpp2min_step<0x128>(m1, m2);
            dpp2min_step<0x142>(m1, m2);
            dpp2min_step<0x143>(m1, m2);
            float s_m1 = readlane_f(m1, 63);
            float s_m2 = readlane_f(m2, 63);

            unsigned long long b0 = __ballot(cur0 == s_m1);
            unsigned long long b1 = __ballot(cur1 == s_m1);
            int j1 = b0 ? __ffsll(b0) : (__ffsll(b1) + 64);  // 1-based column
            int lane1 = (j1 - 1) & 63, slot1 = (j1 - 1) >> 6;

            // u[i] = second-min  (dual-feasible regardless of what follows)
            if (t == l) { if (slotR == 0) uA = s_m2; else uB = s_m2; }

            int k0 = __builtin_amdgcn_readlane(slot1 ? pB : pA, lane1);
            bool strict = (s_m1 < s_m2);
            if (!strict && k0 != 0) continue;  // tie & occupied: leave row free

            if (t == lane1) {
                if (slot1 == 0) { vA += s_m1 - s_m2; pA = i; wA = s_m2; }
                else            { vB += s_m1 - s_m2; pB = i; wB = s_m2; }
            }
            if (slotR == 0) fmA &= ~(1ull << l); else fmB &= ~(1ull << l);
            if (k0 != 0) {  // stolen row becomes free again
                int kl = (k0 - 1) & 63;
                if (k0 <= 64) { fmA |= 1ull << kl; remA |= 1ull << kl; }
                else          { fmB |= 1ull << kl; remB |= 1ull << kl; }
            }
        }
    }

    // ---- Phase 3: Dijkstra shortest augmenting path for leftover free rows ----
    for (int slotR = 0; slotR < 2; ++slotR) {
        unsigned long long mask = slotR ? fmB : fmA;
        while (mask) {
            int l = __ffsll(mask) - 1;
            mask &= mask - 1;
            int i = l + 1 + slotR * 64;  // 1-based free row

            float minvA = FLT_MAX, minvB = FLT_MAX;
            int wayA = 0, wayB = 0;
            bool usedA = false, usedB = false;
            bool rUA = false, rUB = false;
            if (t == l) { if (slotR == 0) rUA = true; else rUB = true; }

            int s_j0 = 0;
            float s_u = readlane_f(slotR ? uB : uA, l);  // u[i] from ARR
            int s_j1;

            // initial row load (row i)
            float c0 = Csh[(i - 1) * Nn + t];
            float c1 = Csh[(i - 1) * Nn + t + 64];

            for (;;) {
                // relax free columns (clamped >= 0 so packed keys order correctly)
                if (!usedA) {
                    float cur = fmaxf(c0 - s_u - vA, 0.0f);
                    if (cur < minvA) { minvA = cur; wayA = s_j0; }
                }
                if (!usedB) {
                    float cur = fmaxf(c1 - s_u - vB, 0.0f);
                    if (cur < minvB) { minvB = cur; wayB = s_j0; }
                }

                // packed-key argmin: (value_bits & ~0xFF) | col0based
                unsigned kA = (__float_as_uint(usedA ? FLT_MAX : minvA) & 0xFFFFFF00u)
                              | (unsigned)t;
                unsigned kB = (__float_as_uint(usedB ? FLT_MAX : minvB) & 0xFFFFFF00u)
                              | (unsigned)(t + 64);
                unsigned k = wave_umin_lane63(min(kA, kB));
                unsigned s_key = (unsigned)__builtin_amdgcn_readlane((int)k, 63);
                float s_delta = __uint_as_float(s_key & 0xFFFFFF00u);
                s_j1 = (int)(s_key & 0xFFu) + 1;  // 1-based column

                // lookup p,w for j1 (needed for prefetch — do before dual updates)
                int lane1 = (s_j1 - 1) & 63;
                int slot1 = (s_j1 - 1) >> 6;
                int s_p = __builtin_amdgcn_readlane(slot1 ? pB : pA, lane1);
                float s_w = readlane_f(slot1 ? wB : wA, lane1);

                // prefetch next cost row (safe index; latency hides under updates)
                int nrow = (s_p > 0 ? s_p : 1) - 1;
                float nc0 = Csh[nrow * Nn + t];
                float nc1 = Csh[nrow * Nn + t + 64];

                // dual updates (independent of prefetch data)
                if (usedA) { vA -= s_delta; wA += s_delta; }
                else       { minvA = fmaxf(minvA - s_delta, 0.0f); }
                if (usedB) { vB -= s_delta; wB += s_delta; }
                else       { minvB = fmaxf(minvB - s_delta, 0.0f); }
                if (rUA) uA += s_delta;
                if (rUB) uB += s_delta;

                if (s_p == 0) break;  // augmenting path found at s_j1

                if (t == lane1) { if (slot1 == 0) usedA = true; else usedB = true; }
                {
                    int r = s_p - 1;
                    if (t == (r & 63)) { if ((r >> 6) == 0) rUA = true; else rUB = true; }
                }
                s_j0 = s_j1;
                s_u = s_w;
                c0 = nc0;
                c1 = nc1;
            }

            // augment along way[] chain (uniform serial walk)
            int s_j = s_j1;
            while (s_j) {
                int lane = (s_j - 1) & 63;
                int slot = (s_j - 1) >> 6;
                int s_jprev = __builtin_amdgcn_readlane(slot ? wayB : wayA, lane);
                int s_pnew;
                if (s_jprev == 0) {
                    s_pnew = i;
                } else {
                    int lp = (s_jprev - 1) & 63;
                    int sp = (s_jprev - 1) >> 6;
                    s_pnew = __builtin_amdgcn_readlane(sp ? pB : pA, lp);
                }
                int rl = (s_pnew - 1) & 63;
                int rs = (s_pnew - 1) >> 6;
                float s_unew = readlane_f(rs ? uB : uA, rl);  // w[j] = u[p[j]]
                if (t == lane) {
                    if (slot == 0) { pA = s_pnew; wA = s_unew; }
                    else           { pB = s_pnew; wB = s_unew; }
                }
                s_j = s_jprev;
            }
        }
    }

    // ---- gather matched costs: column jA=t+1 -> row pA, etc. ----
    float tot = Csh[(pA - 1) * Nn + t] + Csh[(pB - 1) * Nn + t + 64];
    tot = wave_sum_lane63(tot);

    if (t == 63) {
        // loss = sum_b (total_b / N) / B * WEIGHT
        atomicAdd(out, tot * (1.0f / ((float)Nn * (float)Bc)));
    }
}

extern "C" void kernel_launch(void* const* d_in, const int* in_sizes, int n_in,
                              void* d_out, int out_size, void* d_ws, size_t ws_size,
                              hipStream_t stream) {
    const float* P = (const float*)d_in[0];   // batch_prediction  [32,128,256] f32
    const float* G = (const float*)d_in[1];   // batch_groundtruth [32,128,256] f32
    float* out = (float*)d_out;               // [1] f32
    float* C = (float*)d_ws;                  // cost scratch: 32*128*128 f32 = 2 MB

    dim3 gcost(Nn, Bc);
    cost_kernel<<<gcost, 64, 0, stream>>>(P, G, C, out);
    hungarian_kernel<<<Bc, 64, 0, stream>>>(C, out);
}